// Round 1
// 333.907 us; speedup vs baseline: 1.4957x; 1.4957x over previous
//
#include <hip/hip_runtime.h>

// ---------------------------------------------------------------------------
// ChannelAttentionLayer on MI355X (gfx950). Input dtype (fp32 vs bf16) is
// DETECTED ON DEVICE (k_detect); core pipeline is FP16 MFMA + fp32 accumulate.
// R11->R12: attention phase (scores GEMM + softmax + zeroacc + PV + final,
// ~300us at <=13% MfmaUtil) replaced by fused flash-attention k_flash
// (online softmax, S never materialized) + k_merge. Grid 512 = 8 XCD-pinned
// (batch,kt-half) combos x 64 Q-tiles, 2 blocks/CU. Q in regs; K/V staged via
// the proven gld16 XOR-swizzle pattern; P via per-wave-private swizzled LDS.
// St buffer gone -> ws need ~87 MB. Convs unchanged (R6 GEMM structure).
// ---------------------------------------------------------------------------

typedef unsigned short u16;
typedef _Float16 f16x8 __attribute__((ext_vector_type(8)));
typedef __attribute__((ext_vector_type(4))) float f32x4;

__device__ __forceinline__ u16 f2h(float f) {
  _Float16 h = (_Float16)f;
  return *(const u16*)&h;
}
__device__ __forceinline__ float bf2f(u16 h) {
  return __uint_as_float(((unsigned)h) << 16);
}
__device__ __forceinline__ float ldin(const void* p, size_t i, int f32) {
  return f32 ? ((const float*)p)[i] : bf2f(((const u16*)p)[i]);
}
__device__ __forceinline__ u16 f2bf(float f) {
  unsigned u = __float_as_uint(f);
  u += 0x7fffu + ((u >> 16) & 1u);
  return (u16)(u >> 16);
}
__device__ __forceinline__ void gld16(const void* g, void* l) {
  __builtin_amdgcn_global_load_lds(
      (const __attribute__((address_space(1))) unsigned int*)g,
      (__attribute__((address_space(3))) unsigned int*)l, 16, 0, 0);
}

// ---- 1) dtype detection on Wq: 2048 sampled words, 8 independent loads ----
__global__ __launch_bounds__(256) void k_detect(const unsigned* __restrict__ w,
                                                int* __restrict__ flag) {
  __shared__ int red[4];
  int tid = threadIdx.x, cnt = 0;
#pragma unroll
  for (int j = 0; j < 8; j++) {
    unsigned e = (w[tid + j * 8192] >> 7) & 0xFFu;
    cnt += (e >= 118u && e <= 127u) ? 1 : 0;
  }
#pragma unroll
  for (int off = 32; off; off >>= 1) cnt += __shfl_down(cnt, off);
  if ((tid & 63) == 0) red[tid >> 6] = cnt;
  __syncthreads();
  if (tid == 0)
    flag[0] = (red[0] + red[1] + red[2] + red[3] < 625) ? 1 : 0;  // 1 = fp32
}

// ---- 2) pad+transpose x -> fp16 [b][66*66 pix][256c], zero border ----
__global__ __launch_bounds__(256) void k_txp(const void* __restrict__ x,
                                             const int* __restrict__ flag,
                                             u16* __restrict__ xbTp) {
  __shared__ float tile[32][33];
  int f32 = flag[0];
  int b = blockIdx.z, p0 = blockIdx.x * 32, c0 = blockIdx.y * 32;
  int tx = threadIdx.x, ty = threadIdx.y;
#pragma unroll
  for (int i = 0; i < 4; i++) {
    int c = c0 + ty + i * 8, pp = p0 + tx;
    float v = 0.f;
    if (pp < 4356) {
      int yy = pp / 66, xx = pp - yy * 66;
      if (yy >= 1 && yy <= 64 && xx >= 1 && xx <= 64)
        v = ldin(x, ((size_t)b * 256 + c) * 4096 + (yy - 1) * 64 + (xx - 1), f32);
    }
    tile[ty + i * 8][tx] = v;
  }
  __syncthreads();
#pragma unroll
  for (int i = 0; i < 4; i++) {
    int pp = p0 + ty + i * 8;
    if (pp >= 4356) continue;
    xbTp[((size_t)b * 4356 + pp) * 256 + c0 + tx] = f2h(tile[tx][ty + i * 8]);
  }
}

// ---- 3) weight reorders (fp16) ----
__global__ __launch_bounds__(256) void k_wq(const void* __restrict__ Wq,
                                            const int* __restrict__ flag,
                                            u16* __restrict__ WqB) {
  int idx = blockIdx.x * 256 + threadIdx.x;  // 256*2304
  int oc = idx / 2304, rem = idx - oc * 2304;
  int tap = rem >> 8, c = rem & 255;
  WqB[idx] = f2h(ldin(Wq, oc * 2304 + c * 9 + tap, flag[0]));
}
__global__ __launch_bounds__(256) void k_wkv(const void* __restrict__ Wk,
                                             const void* __restrict__ Wv,
                                             const int* __restrict__ flag,
                                             u16* __restrict__ WkvB) {
  int idx = blockIdx.x * 256 + threadIdx.x;  // 512*256
  int m = idx >> 8, c = idx & 255;
  float w = (m < 256) ? ldin(Wk, m * 256 + c, flag[0])
                      : ldin(Wv, (m - 256) * 256 + c, flag[0]);
  WkvB[idx] = f2h(w);
}

// ---- GEMM (fp16): C[M][N] = A[M][K] . Bt[N][K]^T  (R6 1-buf structure) ----
template <bool IMC, int EPI, int SWZ>
__global__ __launch_bounds__(256, 3) void gemm_bt(
    const u16* __restrict__ A, const u16* __restrict__ Bt, void* __restrict__ Cptr,
    int M, int N, int K, int ldB, int tapBase, long long cOff, int kChunk,
    int sw1, int sw2, int nSplit, long long zA, long long zB, long long zC) {
  __shared__ u16 lA[128 * 64];
  __shared__ u16 lB[128 * 64];
  int tm, tn, b = 0, kz = 0;
  if (SWZ == 1) {
    int lin = blockIdx.x, xcd = lin & 7, per = lin >> 3;
    tm = xcd * sw1 + (per % sw1);
    tn = per / sw1;
    b = blockIdx.y;
  } else if (SWZ == 2) {
    int lin = blockIdx.x, xcd = lin & 7, per = lin >> 3;
    tm = per % sw1;
    tn = xcd * sw2 + per / sw1;
    kz = blockIdx.z;
  } else {
    tm = blockIdx.x;
    tn = blockIdx.y;
    b = blockIdx.z / nSplit;
    kz = blockIdx.z % nSplit;
  }
  int k0 = 0, k1 = K;
  if (kChunk) {
    k0 = kz * kChunk;
    k1 = min(k0 + kChunk, K);
  }
  const int tid = threadIdx.x, wave = tid >> 6, lane = tid & 63;
  const int sr = lane >> 3;         // source row within 8-row issue group
  const int scw = (lane & 7) ^ sr;  // XOR-swizzled source chunk
  const int wm = (wave >> 1) * 64, wn = (wave & 1) * 64;
  const int r16 = lane & 15, q = lane >> 4;
  const u16* gA = A + (size_t)b * zA + (size_t)(tm * 128 + wave * 32 + sr) * K +
                  scw * 8;
  const u16* gB = nullptr;
  int pyI[4], pxI[4];
  size_t bOffI[4];
  if (IMC) {
#pragma unroll
    for (int i = 0; i < 4; i++) {
      int n = tn * 128 + wave * 32 + i * 8 + sr;  // global output pixel
      int bb = n >> 12, pix = n & 4095;
      pyI[i] = pix >> 6;
      pxI[i] = pix & 63;
      bOffI[i] = (size_t)bb * 4356;
    }
  } else {
    gB = Bt + (size_t)b * zB + (size_t)(tn * 128 + wave * 32 + sr) * ldB +
         scw * 8;
  }
  f32x4 acc[4][4] = {};

  for (int kt = k0; kt < k1; kt += 64) {
    int dy = 0, dx = 0, chunk = 0;
    if (IMC) {
      int tap = tapBase + (kt >> 8);
      chunk = kt & 255;
      dy = tap / 3;
      dx = tap - dy * 3;
    }
#pragma unroll
    for (int i = 0; i < 4; i++) {
      gld16(gA + (size_t)(i * 8) * K + kt, &lA[(wave * 32 + i * 8) * 64]);
      if (IMC) {
        int spix = (pyI[i] + dy) * 66 + pxI[i] + dx;
        gld16(Bt + (bOffI[i] + spix) * 256 + chunk + scw * 8,
              &lB[(wave * 32 + i * 8) * 64]);
      } else {
        gld16(gB + (size_t)(i * 8) * ldB + kt, &lB[(wave * 32 + i * 8) * 64]);
      }
    }
    __syncthreads();
#pragma unroll
    for (int ks = 0; ks < 64; ks += 32) {
      f16x8 af[4], bfr[4];
#pragma unroll
      for (int f = 0; f < 4; f++) {
        int ma = wm + f * 16 + r16;
        int g = (ks >> 3) + q;
        af[f] = *(const f16x8*)&lA[ma * 64 + ((g ^ (ma & 7)) << 3)];
        int nb = wn + f * 16 + r16;
        bfr[f] = *(const f16x8*)&lB[nb * 64 + ((g ^ (nb & 7)) << 3)];
      }
#pragma unroll
      for (int fi = 0; fi < 4; fi++)
#pragma unroll
        for (int fj = 0; fj < 4; fj++)
          acc[fi][fj] = __builtin_amdgcn_mfma_f32_16x16x32_f16(
              af[fi], bfr[fj], acc[fi][fj], 0, 0, 0);
    }
    __syncthreads();
  }

  const int colB = tn * 128 + wn + r16;
  const int rowB = tm * 128 + wm + q * 4;
  float* C = (float*)Cptr + cOff + (size_t)b * zC;
  if (EPI == 0) {
#pragma unroll
    for (int fi = 0; fi < 4; fi++)
#pragma unroll
      for (int r = 0; r < 4; r++) {
        size_t ro = (size_t)(rowB + fi * 16 + r) * N;
#pragma unroll
        for (int fj = 0; fj < 4; fj++) C[ro + colB + fj * 16] = acc[fi][fj][r];
      }
  } else {
#pragma unroll
    for (int fi = 0; fi < 4; fi++)
#pragma unroll
      for (int r = 0; r < 4; r++) {
        size_t ro = (size_t)(rowB + fi * 16 + r) * N;
#pragma unroll
        for (int fj = 0; fj < 4; fj++)
          atomicAdd(&C[ro + colB + fj * 16], acc[fi][fj][r]);
      }
  }
}

// ---- 5) BN stats (biases cancel; K/V border conv-value 0, count 17424) ----
__global__ __launch_bounds__(256) void k_stats(
    const float* __restrict__ bufQ, const float* __restrict__ bufKV,
    const void* __restrict__ gq, const void* __restrict__ betaq,
    const void* __restrict__ gk, const void* __restrict__ betak,
    const void* __restrict__ gv, const void* __restrict__ betav,
    const int* __restrict__ flag, float* __restrict__ nrm) {
  int f32 = flag[0];
  int ch = blockIdx.x, t = blockIdx.y, tid = threadIdx.x;
  const float* row = (t == 0) ? bufQ + (size_t)ch * 16384
                              : bufKV + (size_t)(t == 1 ? ch : 256 + ch) * 16384;
  float s = 0.f, ss = 0.f;
  for (int i = tid; i < 16384; i += 256) {
    float v = row[i];
    s += v;
    ss += v * v;
  }
#pragma unroll
  for (int off = 32; off; off >>= 1) {
    s += __shfl_down(s, off);
    ss += __shfl_down(ss, off);
  }
  __shared__ float ls[4], lss[4];
  if ((tid & 63) == 0) {
    ls[tid >> 6] = s;
    lss[tid >> 6] = ss;
  }
  __syncthreads();
  if (tid == 0) {
    s = ls[0] + ls[1] + ls[2] + ls[3];
    ss = lss[0] + lss[1] + lss[2] + lss[3];
    float cnt = (t == 0) ? 16384.f : 17424.f;
    float mean = s / cnt;
    float var = fmaxf(ss / cnt - mean * mean, 0.f);  // NaN-proof
    const void* g = (t == 0) ? gq : (t == 1 ? gk : gv);
    const void* be = (t == 0) ? betaq : (t == 1 ? betak : betav);
    float sc = ldin(g, ch, f32) * rsqrtf(var + 1e-5f);
    nrm[(t * 256 + ch) * 2] = sc;
    nrm[(t * 256 + ch) * 2 + 1] = ldin(be, ch, f32) - mean * sc;
  }
}

// ---- 6) normalize + transpose to fp16 (K=256 rows) ----
__global__ __launch_bounds__(256) void k_qTs(const float* __restrict__ bufQ,
                                             const float* __restrict__ nrm,
                                             u16* __restrict__ qTs) {
  __shared__ u16 th[32][33];
  int b = blockIdx.z, q0 = blockIdx.x * 32, c0 = blockIdx.y * 32;
  int tx = threadIdx.x, ty = threadIdx.y;
#pragma unroll
  for (int i = 0; i < 4; i++) {
    int c = c0 + ty + i * 8;
    float sc = nrm[c * 2], sh = nrm[c * 2 + 1];
    th[ty + i * 8][tx] =
        f2h(bufQ[(size_t)c * 16384 + b * 4096 + q0 + tx] * sc + sh);
  }
  __syncthreads();
#pragma unroll
  for (int i = 0; i < 4; i++)
    qTs[((size_t)b * 4096 + q0 + ty + i * 8) * 256 + c0 + tx] =
        th[tx][ty + i * 8];
}
__global__ __launch_bounds__(256) void k_kTs(const float* __restrict__ bufKV,
                                             const float* __restrict__ nrm,
                                             u16* __restrict__ kTs) {
  __shared__ u16 th[32][33];
  int b = blockIdx.z, k0 = blockIdx.x * 32, c0 = blockIdx.y * 32;
  int tx = threadIdx.x, ty = threadIdx.y;
#pragma unroll
  for (int i = 0; i < 4; i++) {
    int c = c0 + ty + i * 8;
    int kt = k0 + tx;
    float v = 0.f;
    if (kt < 4356) {
      float sc = nrm[(256 + c) * 2], sh = nrm[(256 + c) * 2 + 1];
      int yy = kt / 66, xx = kt - yy * 66;
      if (yy >= 1 && yy <= 64 && xx >= 1 && xx <= 64)
        v = bufKV[(size_t)c * 16384 + b * 4096 + (yy - 1) * 64 + (xx - 1)] * sc + sh;
      else
        v = sh;  // border: conv value 0
    }
    th[ty + i * 8][tx] = f2h(v);  // kt >= 4356 rows -> exact zeros
  }
  __syncthreads();
#pragma unroll
  for (int i = 0; i < 4; i++)
    kTs[((size_t)b * 4480 + k0 + ty + i * 8) * 256 + c0 + tx] =
        th[tx][ty + i * 8];
}

// ---- 7) normalized V fp16, [b][c][4480], pads zero ----
__global__ __launch_bounds__(256) void k_vP(const float* __restrict__ bufKV,
                                            const float* __restrict__ nrm,
                                            u16* __restrict__ vP) {
  int b = blockIdx.z, ch = blockIdx.y;
  int kt = blockIdx.x * 256 + threadIdx.x;
  if (kt >= 4480) return;
  float v = 0.f;
  if (kt < 4356) {
    float sc = nrm[(512 + ch) * 2], sh = nrm[(512 + ch) * 2 + 1];
    int yy = kt / 66, xx = kt - yy * 66;
    if (yy >= 1 && yy <= 64 && xx >= 1 && xx <= 64)
      v = bufKV[(size_t)(256 + ch) * 16384 + b * 4096 + (yy - 1) * 64 + (xx - 1)] * sc + sh;
    else
      v = sh;
  }
  vP[((size_t)b * 256 + ch) * 4480 + kt] = f2h(v);
}

// ---- 8) fused flash attention ----
// grid 512 linear: xcd = lin&7 pins (h = xcd&1, b = xcd>>1) per XCD so each
// XCD L2 caches its (batch, kt-half) K/V (~4.6 MB); per = lin>>3 -> qt tile.
// Block: 64 qt x 256 c, 4 waves, each wave owns 16 qt for S, softmax AND PV
// (fi=1 / fj=16) -> P tile is per-wave private (no cross-wave barriers for it).
// kt-half h: [0,2304) = 18 tiles / [2304,4480) = 17 tiles of 128.
// Outputs fp32 partial O [h][b][4096][256] + (m,l) per row; k_merge combines.
__global__ __launch_bounds__(256, 2) void k_flash(
    const u16* __restrict__ qTs, const u16* __restrict__ kTs,
    const u16* __restrict__ vP, float* __restrict__ Op,
    float* __restrict__ ml) {
  __shared__ u16 lU[2][128 * 64];  // 32 KB: K-tile half (2 kc chunks) / V chunk
  __shared__ u16 lP[64 * 128];     // 16 KB: P tile fp16, XOR-swizzled
  const int lin = blockIdx.x;
  const int xcd = lin & 7, per = lin >> 3;
  const int h = xcd & 1, b = xcd >> 1;
  const int qt0 = per * 64;
  const int tid = threadIdx.x, wave = tid >> 6, lane = tid & 63;
  const int sr = lane >> 3, scw = (lane & 7) ^ sr;
  const int r16 = lane & 15, q = lane >> 4;

  // Q fragments in registers: aq[kk] = Q[qt0+wave*16+r16][kk*32 + q*8 ..+7]
  const u16* gQ = qTs + ((size_t)b * 4096 + qt0 + wave * 16 + r16) * 256;
  f16x8 aq[8];
#pragma unroll
  for (int kk = 0; kk < 8; kk++) aq[kk] = *(const f16x8*)&gQ[kk * 32 + q * 8];

  const u16* gK = kTs + (size_t)b * 4480 * 256 + (size_t)(wave * 32 + sr) * 256 + scw * 8;
  const u16* gV = vP + ((size_t)b * 256 + wave * 64 + sr) * 4480 + scw * 8;

  f32x4 acc_o[16];
#pragma unroll
  for (int i = 0; i < 16; i++) acc_o[i] = (f32x4){0.f, 0.f, 0.f, 0.f};
  f32x4 m_v = {-3e38f, -3e38f, -3e38f, -3e38f};
  f32x4 l_v = {0.f, 0.f, 0.f, 0.f};

  const int ktBeg = h ? 2304 : 0, ktEnd = h ? 4480 : 2304;
  for (int kt0 = ktBeg; kt0 < ktEnd; kt0 += 128) {
    f32x4 acc_s[8];
#pragma unroll
    for (int i = 0; i < 8; i++) acc_s[i] = (f32x4){0.f, 0.f, 0.f, 0.f};
    // ---- S = Q.K^T, K staged in two 32KB halves (kc pairs) ----
#pragma unroll
    for (int c2 = 0; c2 < 2; c2++) {
#pragma unroll
      for (int i = 0; i < 4; i++) {
        const u16* src = gK + (size_t)(kt0 + i * 8) * 256 + c2 * 128;
        gld16(src, &lU[0][(wave * 32 + i * 8) * 64]);
        gld16(src + 64, &lU[1][(wave * 32 + i * 8) * 64]);
      }
      __syncthreads();  // K chunks ready (drains vmcnt); prior lU reads done
#pragma unroll
      for (int kcL = 0; kcL < 2; kcL++)
#pragma unroll
        for (int ks = 0; ks < 64; ks += 32)
#pragma unroll
          for (int fj = 0; fj < 8; fj++) {
            int nb = fj * 16 + r16;
            int g = (ks >> 3) + q;
            f16x8 bf = *(const f16x8*)&lU[kcL][nb * 64 + ((g ^ (nb & 7)) << 3)];
            acc_s[fj] = __builtin_amdgcn_mfma_f32_16x16x32_f16(
                aq[c2 * 4 + kcL * 2 + (ks >> 5)], bf, acc_s[fj], 0, 0, 0);
          }
      __syncthreads();  // lU reads done before restage / V stage
    }
    // ---- mask pad keys (only last tile; kTs pad rows are zeros, no NaN) ----
    if (kt0 + 128 > 4356) {
#pragma unroll
      for (int fj = 0; fj < 8; fj++)
        if (kt0 + fj * 16 + r16 >= 4356)
          acc_s[fj] = (f32x4){-1e30f, -1e30f, -1e30f, -1e30f};
    }
    // ---- online softmax; lane owns rows q*4+rr of wave's 16-qt strip ----
    f32x4 pm = acc_s[0];
#pragma unroll
    for (int fj = 1; fj < 8; fj++)
#pragma unroll
      for (int rr = 0; rr < 4; rr++) pm[rr] = fmaxf(pm[rr], acc_s[fj][rr]);
#pragma unroll
    for (int d = 1; d < 16; d <<= 1)
#pragma unroll
      for (int rr = 0; rr < 4; rr++)
        pm[rr] = fmaxf(pm[rr], __shfl_xor(pm[rr], d));
    f32x4 mn, fac;
#pragma unroll
    for (int rr = 0; rr < 4; rr++) {
      mn[rr] = fmaxf(m_v[rr], pm[rr]);
      fac[rr] = __expf(m_v[rr] - mn[rr]);
    }
    f32x4 rs = {0.f, 0.f, 0.f, 0.f};
#pragma unroll
    for (int fj = 0; fj < 8; fj++)
#pragma unroll
      for (int rr = 0; rr < 4; rr++) {
        _Float16 hp = (_Float16)__expf(acc_s[fj][rr] - mn[rr]);
        rs[rr] += (float)hp;  // denominator sums the rounded p (consistency)
        int row = wave * 16 + q * 4 + rr;
        int c8 = fj * 2 + (r16 >> 3);
        lP[row * 128 + (((c8 ^ (row & 15)) << 3) | (r16 & 7))] = *(const u16*)&hp;
      }
#pragma unroll
    for (int d = 1; d < 16; d <<= 1)
#pragma unroll
      for (int rr = 0; rr < 4; rr++) rs[rr] += __shfl_xor(rs[rr], d);
#pragma unroll
    for (int rr = 0; rr < 4; rr++) {
      l_v[rr] = l_v[rr] * fac[rr] + rs[rr];
      m_v[rr] = mn[rr];
    }
#pragma unroll
    for (int fj = 0; fj < 16; fj++)
#pragma unroll
      for (int rr = 0; rr < 4; rr++) acc_o[fj][rr] *= fac[rr];
    // ---- PV: O += P.V^T, V staged in two 32KB chunks; P read in-wave ----
#pragma unroll
    for (int vc = 0; vc < 2; vc++) {
#pragma unroll
      for (int i = 0; i < 8; i++)
        gld16(gV + (size_t)(i * 8) * 4480 + kt0 + vc * 64,
              &((u16*)lU)[(wave * 64 + i * 8) * 64]);
      __syncthreads();  // V ready; prior lU reads done
#pragma unroll
      for (int ks = 0; ks < 64; ks += 32) {
        int k8 = vc * 8 + (ks >> 3) + q;
        f16x8 ap = *(const f16x8*)&lP[(wave * 16 + r16) * 128 + ((k8 ^ r16) << 3)];
#pragma unroll
        for (int fj = 0; fj < 16; fj++) {
          int nb = fj * 16 + r16;
          int g = (ks >> 3) + q;
          f16x8 bv = *(const f16x8*)&((u16*)lU)[nb * 64 + ((g ^ (nb & 7)) << 3)];
          acc_o[fj] = __builtin_amdgcn_mfma_f32_16x16x32_f16(ap, bv, acc_o[fj], 0, 0, 0);
        }
      }
      __syncthreads();  // lU reads done before next stage
    }
  }
  // ---- store partials ----
  size_t ob = ((size_t)(h * 4 + b) * 4096 + qt0 + wave * 16) * 256;
#pragma unroll
  for (int rr = 0; rr < 4; rr++) {
    size_t rowo = ob + (size_t)(q * 4 + rr) * 256;
#pragma unroll
    for (int fj = 0; fj < 16; fj++) Op[rowo + fj * 16 + r16] = acc_o[fj][rr];
  }
  if (r16 == 0) {
    int base = (h * 4 + b) * 4096 + qt0 + wave * 16 + q * 4;
    *(f32x4*)&ml[base] = m_v;
    *(f32x4*)&ml[32768 + base] = l_v;
  }
}

// ---- 9) merge two kt-half partials, divide, transpose to out[b][c][qt] ----
__global__ __launch_bounds__(256) void k_merge(const float* __restrict__ Op,
                                               const float* __restrict__ ml,
                                               const int* __restrict__ flag,
                                               void* __restrict__ out) {
  __shared__ float th[32][33];
  int b = blockIdx.z, qt0 = blockIdx.x * 32, c0 = blockIdx.y * 32;
  int tx = threadIdx.x, ty = threadIdx.y;
#pragma unroll
  for (int i = 0; i < 4; i++) {
    int qt = qt0 + ty + i * 8;
    float m0 = ml[b * 4096 + qt], m1 = ml[(4 + b) * 4096 + qt];
    float l0 = ml[32768 + b * 4096 + qt], l1 = ml[32768 + (4 + b) * 4096 + qt];
    float M = fmaxf(m0, m1);
    float e0 = __expf(m0 - M), e1 = __expf(m1 - M);
    float inv = 1.f / (l0 * e0 + l1 * e1);  // >= 1, safe
    float v = (Op[((size_t)b * 4096 + qt) * 256 + c0 + tx] * e0 +
               Op[((size_t)(4 + b) * 4096 + qt) * 256 + c0 + tx] * e1) * inv;
    v = (v == v) ? v : 0.f;  // NaN scrub: keep failures diagnostic
    th[ty + i * 8][tx] = v;
  }
  __syncthreads();
#pragma unroll
  for (int i = 0; i < 4; i++) {
    int c = c0 + ty + i * 8, qt = qt0 + tx;
    float v = th[tx][ty + i * 8];
    size_t oidx = ((size_t)b * 256 + c) * 4096 + qt;
    if (flag[0])
      ((float*)out)[oidx] = v;
    else
      ((u16*)out)[oidx] = f2bf(v);
  }
}

// ---- 10) split-K support for conv ----
__global__ __launch_bounds__(256) void k_zeroacc(float* __restrict__ accF) {
  accF[blockIdx.x * 256 + threadIdx.x] = 0.f;
}

// ---------------------------------------------------------------------------
extern "C" void kernel_launch(void* const* d_in, const int* in_sizes, int n_in,
                              void* d_out, int out_size, void* d_ws, size_t ws_size,
                              hipStream_t stream) {
  const void* x = d_in[0];
  const void* Wq = d_in[1];
  const void* gq = d_in[3];
  const void* betaq = d_in[4];
  const void* Wk = d_in[5];
  const void* gk = d_in[7];
  const void* betak = d_in[8];
  const void* Wv = d_in[9];
  const void* gv = d_in[11];
  const void* betav = d_in[12];

  char* ws = (char*)d_ws;
  int* flag = (int*)ws;  // 256 B
  // Region A (conv phase; dead once qTs/kTs/vP built -> overlaid by Opart/ml):
  u16* xbTp = (u16*)(ws + 256);            //  8,921,088
  u16* WqB = (u16*)(ws + 8921344);         //  1,179,648
  u16* WkvB = (u16*)(ws + 10100992);       //    262,144
  float* bufQ = (float*)(ws + 10363136);   // 16,777,216
  float* bufKV = (float*)(ws + 27140352);  // 33,554,432 -> A ends 60,694,784
  u16* qTs = (u16*)(ws + 60694784);        //  8,388,608 (4*4096*256*2)
  u16* kTs = (u16*)(ws + 69083392);        //  9,175,040 (4*4480*256*2)
  u16* vP = (u16*)(ws + 78258432);         //  9,175,040
  float* nrm = (float*)(ws + 87433472);    //      6,144 -> total 87,439,616 B
  // Overlay region A (dead by flash time):
  float* Opart = (float*)(ws + 256);       // 33,554,432 (2*4*4096*256*4)
  float* mlbuf = (float*)(ws + 33554688);  //    262,144 (m: 32768 f, l: 32768 f)

  dim3 b32x8(32, 8);
  k_detect<<<1, 256, 0, stream>>>((const unsigned*)Wq, flag);
  k_txp<<<dim3(137, 8, 4), b32x8, 0, stream>>>(x, flag, xbTp);
  k_wq<<<2304, 256, 0, stream>>>(Wq, flag, WqB);
  k_wkv<<<512, 256, 0, stream>>>(Wk, Wv, flag, WkvB);
  // conv3x3: K=2304 split-K x3 (chunk 768) into zeroed bufQ; 768 blocks.
  k_zeroacc<<<16384, 256, 0, stream>>>(bufQ);
  gemm_bt<true, 1, 2><<<dim3(256, 1, 3), 256, 0, stream>>>(
      WqB, xbTp, bufQ, 256, 16384, 2304, 0, 0, 0, 768, 2, 16, 1, 0, 0, 0);
  // conv1x1: K=256; grid 512 = 8 XCD x (4 tm x 16 tn-band)
  gemm_bt<true, 0, 2><<<512, 256, 0, stream>>>(
      WkvB, xbTp, bufKV, 512, 16384, 256, 0, 4, 0, 0, 4, 16, 1, 0, 0, 0);
  k_stats<<<dim3(256, 3), 256, 0, stream>>>(bufQ, bufKV, gq, betaq, gk, betak,
                                            gv, betav, flag, nrm);
  k_qTs<<<dim3(128, 8, 4), b32x8, 0, stream>>>(bufQ, nrm, qTs);
  k_kTs<<<dim3(140, 8, 4), b32x8, 0, stream>>>(bufKV, nrm, kTs);
  k_vP<<<dim3(18, 256, 4), 256, 0, stream>>>(bufKV, nrm, vP);
  // fused attention: 512 blocks = 8 XCD-combos x 64 qt tiles, 2 blocks/CU
  k_flash<<<512, 256, 0, stream>>>(qTs, kTs, vP, Opart, mlbuf);
  k_merge<<<dim3(128, 8, 4), b32x8, 0, stream>>>(Opart, mlbuf, flag, d_out);
}